// Round 1
// baseline (1996.487 us; speedup 1.0000x reference)
//
#include <hip/hip_runtime.h>

#define B_ 2048
#define T_ 1024
#define D_ 64
#define H_ 16

constexpr float INV_TAU = 1.0f / 6.0f;
constexpr float U_ = 0.5f;

// ---------------------------------------------------------------------------
// K1: synaptic-depression scan over t, one thread per (b,d).
// Writes x_cat[b][t][0:64]=inputs, x_cat[b][t][64:128]=syn*inputs.
// Memory-bound: R 512MiB + W 1GiB. 8-deep prefetch hides HBM latency at
// 2 waves/SIMD occupancy.
// ---------------------------------------------------------------------------
__global__ __launch_bounds__(256) void syn_kernel(
    const float* __restrict__ inputs, const float* __restrict__ synx0,
    float* __restrict__ xcat) {
  int gid = blockIdx.x * 256 + threadIdx.x;
  int b = gid >> 6;
  int d = gid & 63;
  const float* ip = inputs + (size_t)b * T_ * D_ + d;
  float* xc = xcat + (size_t)b * T_ * (2 * D_) + d;
  float s = synx0[b * D_ + d];

  float cur[8];
#pragma unroll
  for (int i = 0; i < 8; i++) cur[i] = ip[(size_t)i * D_];

  for (int t0 = 0; t0 < T_; t0 += 8) {
    float nxt[8] = {0, 0, 0, 0, 0, 0, 0, 0};
    if (t0 + 8 < T_) {
#pragma unroll
      for (int i = 0; i < 8; i++) nxt[i] = ip[(size_t)(t0 + 8 + i) * D_];
    }
#pragma unroll
    for (int i = 0; i < 8; i++) {
      float x = cur[i];
      float k = fmaf(U_, x, INV_TAU);          // k = 1/tau + 0.5*x  (>= 1/6)
      float e = __expf(-k);
      float t1 = fmaf(-s, k, INV_TAU);         // inv_tau - s*k
      float t2 = fmaf(-t1, e, INV_TAU);        // inv_tau - t1*e
      float y = s * x;                         // emit PRE-update s
      xc[(size_t)(t0 + i) * (2 * D_)] = x;
      xc[(size_t)(t0 + i) * (2 * D_) + D_] = y;
      s = t2 / k;                              // IEEE div, matches np closely
    }
#pragma unroll
    for (int i = 0; i < 8; i++) cur[i] = nxt[i];
  }
}

// ---------------------------------------------------------------------------
// K2: xw[b][t][h] = bias[h] + sum_j x_cat[b][t][j] * W_ih[j][h]
// Block = 256 threads = one t, 64 consecutive b. x_cat tile staged in LDS
// as [j][b] with stride 65 (compute reads conflict-free: bank=(j+b)%32,
// 2-way). W_ih staged in LDS, read as float4 16-lane broadcast (free).
// Thread (b = i>>2, hq = (i&3)*4) keeps 4 fp32 accumulators:
// per j: 1 ds_read_b32 + 1 ds_read_b128 + 4 fma  -> issue ~85us < mem ~180us.
// Output written into the *hidden region* of d_out (consumed+overwritten by K3).
// ---------------------------------------------------------------------------
__global__ __launch_bounds__(256) void proj_kernel(
    const float* __restrict__ xcat, const float* __restrict__ wih,
    const float* __restrict__ bias, float* __restrict__ xw) {
  __shared__ float xs[128 * 65];                 // [j][b], +1 pad row stride
  __shared__ __align__(16) float wl[128 * 16];   // [j][h]
  int i = threadIdx.x;
  int t = blockIdx.x >> 5;
  int b0 = (blockIdx.x & 31) * 64;

  // stage W_ih (2048 floats, 8 per thread)
  {
    float4 v0 = *(const float4*)(wih + i * 8);
    float4 v1 = *(const float4*)(wih + i * 8 + 4);
    *(float4*)(wl + i * 8) = v0;
    *(float4*)(wl + i * 8 + 4) = v1;
  }
  // stage x_cat[b0:b0+64][t][0:128]: coalesced float4 loads (32 lanes = 1 row)
#pragma unroll
  for (int it = 0; it < 8; it++) {
    int slot = it * 256 + i;
    int br = slot >> 5;   // 0..63
    int c4 = slot & 31;   // 0..31  (j-quad)
    float4 v = *(const float4*)(xcat + ((size_t)(b0 + br) * T_ + t) * 128 + c4 * 4);
    xs[(c4 * 4 + 0) * 65 + br] = v.x;   // 4-way bank conflict on writes only
    xs[(c4 * 4 + 1) * 65 + br] = v.y;
    xs[(c4 * 4 + 2) * 65 + br] = v.z;
    xs[(c4 * 4 + 3) * 65 + br] = v.w;
  }
  __syncthreads();

  int hq = (i & 3) * 4;   // h quad: 0,4,8,12
  int b = i >> 2;         // 0..63
  float4 acc = *(const float4*)(bias + hq);
#pragma unroll
  for (int j = 0; j < 128; j++) {
    float x = xs[j * 65 + b];
    float4 w = *(const float4*)(wl + j * 16 + hq);
    acc.x = fmaf(x, w.x, acc.x);
    acc.y = fmaf(x, w.y, acc.y);
    acc.z = fmaf(x, w.z, acc.z);
    acc.w = fmaf(x, w.w, acc.w);
  }
  *(float4*)(xw + ((size_t)(b0 + b) * T_ + t) * H_ + hq) = acc;
}

// ---------------------------------------------------------------------------
// K3: RNN scan. One wave per 4 batch rows: lane = (bsub<<4) | h.
// h state per lane; h-exchange via __shfl (wave-safe, no barrier).
// W_hh column preloaded in 16 VGPRs/lane. Reads xw[b][t][h] and overwrites
// the same location with hidden[b][t][h] (read always precedes write, same
// thread). 4-deep register prefetch of xw.
// ---------------------------------------------------------------------------
__global__ __launch_bounds__(64) void rnn_kernel(
    const float* __restrict__ h0, const float* __restrict__ whh,
    float* xwh /* in-place: xw -> hidden, [b][t][h] */) {
  int lane = threadIdx.x;
  int bs = lane >> 4;
  int myh = lane & 15;
  int b = blockIdx.x * 4 + bs;
  int gbase = bs << 4;

  float w[16];
#pragma unroll
  for (int i = 0; i < 16; i++) w[i] = whh[i * 16 + myh];

  float h = h0[b * H_ + myh];
  float* xp = xwh + (size_t)b * T_ * H_ + myh;

  float p0 = xp[0 * 16], p1 = xp[1 * 16], p2 = xp[2 * 16], p3 = xp[3 * 16];
  for (int t = 0; t < T_; t += 4) {
    float x0 = p0, x1 = p1, x2 = p2, x3 = p3;
    if (t + 4 < T_) {
      p0 = xp[(size_t)(t + 4) * 16];
      p1 = xp[(size_t)(t + 5) * 16];
      p2 = xp[(size_t)(t + 6) * 16];
      p3 = xp[(size_t)(t + 7) * 16];
    }
#pragma unroll
    for (int u = 0; u < 4; u++) {
      float xv = (u == 0) ? x0 : (u == 1) ? x1 : (u == 2) ? x2 : x3;
      float a0 = xv, a1 = 0.f, a2 = 0.f, a3 = 0.f;
#pragma unroll
      for (int ii = 0; ii < 4; ii++) {
        a0 = fmaf(__shfl(h, gbase + ii),      w[ii],      a0);
        a1 = fmaf(__shfl(h, gbase + 4 + ii),  w[4 + ii],  a1);
        a2 = fmaf(__shfl(h, gbase + 8 + ii),  w[8 + ii],  a2);
        a3 = fmaf(__shfl(h, gbase + 12 + ii), w[12 + ii], a3);
      }
      h = fmaxf((a0 + a1) + (a2 + a3), 0.0f);
      xp[(size_t)(t + u) * 16] = h;   // hidden[b][t][h], overwrites consumed xw
    }
  }
}

// ---------------------------------------------------------------------------
// K4: output[b,t] = hidden[b,t,:] @ lin_w + lin_b. Streaming; lin_w via
// uniform (scalar) loads. ~142 MiB traffic.
// ---------------------------------------------------------------------------
__global__ __launch_bounds__(256) void out_kernel(
    const float* __restrict__ hid, const float* __restrict__ lw,
    const float* __restrict__ lb, float* __restrict__ out) {
  int i = blockIdx.x * 256 + threadIdx.x;  // 0 .. B*T-1
  const float* hp = hid + (size_t)i * H_;
  float4 h0 = *(const float4*)(hp);
  float4 h1 = *(const float4*)(hp + 4);
  float4 h2 = *(const float4*)(hp + 8);
  float4 h3 = *(const float4*)(hp + 12);
  float acc = lb[0];
  acc = fmaf(h0.x, lw[0], acc);  acc = fmaf(h0.y, lw[1], acc);
  acc = fmaf(h0.z, lw[2], acc);  acc = fmaf(h0.w, lw[3], acc);
  acc = fmaf(h1.x, lw[4], acc);  acc = fmaf(h1.y, lw[5], acc);
  acc = fmaf(h1.z, lw[6], acc);  acc = fmaf(h1.w, lw[7], acc);
  acc = fmaf(h2.x, lw[8], acc);  acc = fmaf(h2.y, lw[9], acc);
  acc = fmaf(h2.z, lw[10], acc); acc = fmaf(h2.w, lw[11], acc);
  acc = fmaf(h3.x, lw[12], acc); acc = fmaf(h3.y, lw[13], acc);
  acc = fmaf(h3.z, lw[14], acc); acc = fmaf(h3.w, lw[15], acc);
  out[i] = acc;
}

// ---------------------------------------------------------------------------
extern "C" void kernel_launch(void* const* d_in, const int* in_sizes, int n_in,
                              void* d_out, int out_size, void* d_ws,
                              size_t ws_size, hipStream_t stream) {
  const float* inputs = (const float*)d_in[0];  // [B,T,D]
  const float* synx0  = (const float*)d_in[1];  // [B,D]
  const float* h0     = (const float*)d_in[2];  // [B,H]
  const float* wih    = (const float*)d_in[3];  // [2D,H]
  const float* whh    = (const float*)d_in[4];  // [H,H]
  const float* bias   = (const float*)d_in[5];  // [H]
  const float* lw     = (const float*)d_in[6];  // [H,1]
  const float* lb     = (const float*)d_in[7];  // [1]

  float* out  = (float*)d_out;                       // [B,T,1]
  float* hid  = out + (size_t)B_ * T_;               // [B,T,H]
  float* xcat = hid + (size_t)B_ * T_ * H_;          // [B,T,2D]

  // K1: syn scan -> x_cat
  syn_kernel<<<(B_ * D_) / 256, 256, 0, stream>>>(inputs, synx0, xcat);
  // K2: projection -> xw staged in hidden region ([b][t][h])
  proj_kernel<<<T_ * (B_ / 64), 256, 0, stream>>>(xcat, wih, bias, hid);
  // K3: RNN scan, in-place xw -> hidden
  rnn_kernel<<<B_ / 4, 64, 0, stream>>>(h0, whh, hid);
  // K4: output projection
  out_kernel<<<(B_ * T_) / 256, 256, 0, stream>>>(hid, lw, lb, out);
}